// Round 16
// baseline (57.073 us; speedup 1.0000x reference)
//
#include <hip/hip_runtime.h>
#include <hip/hip_fp16.h>

#define NN 50000
#define NE 800000
#define D  64
#define NBUK  256
#define NBLKS 500            // scatter chunks: 500 x 1600 = 800000 exactly
#define CHUNK2 1600          // multiple of 4 -> uint4 edge reads
#define FS 68                // feat LDS stride (pad 64 -> 68)
#define GEMMB 782            // ceil(NN/64) gemm tiles
#define BCAP 4608            // fixed bucket capacity (mean 4096, sd 64 -> 8 sigma)

typedef float __attribute__((ext_vector_type(4))) f32x4;

// ---------------------------------------------------------------------------
// block-wide exclusive scan of one int per thread (256 threads = 4 waves).
__device__ inline int block_exscan(int val, int tid) {
    __shared__ int wsum[4];
    int lane = tid & 63, w = tid >> 6;
    int v = val;
    #pragma unroll
    for (int d = 1; d < 64; d <<= 1) {
        int t = __shfl_up(v, d);
        if (lane >= d) v += t;
    }
    if (lane == 63) wsum[w] = v;
    __syncthreads();
    int base = 0;
    #pragma unroll
    for (int i = 0; i < 4; ++i) base += (i < w) ? wsum[i] : 0;
    __syncthreads();
    return base + v - val;   // exclusive
}

// ---------------------------------------------------------------------------
// K1: fused gemm + single-pass direct-placement bucket scatter (role split).
// scatter blocks [0,NBLKS): LDS hist of own chunk -> ONE global atomicAdd per
// bucket reserves space in the bucket's FIXED segment [t*BCAP, (t+1)*BCAP) ->
// scatter packed (row | (col&255)<<16). No global scan pass needed.
// gemm blocks [NBLKS, NBLKS+GEMMB): y_raw[r][d] = fp16(feat[r].W[:,d]).
__global__ __launch_bounds__(256) void k_gemm_bucket(const int* __restrict__ row,
                                                     const int* __restrict__ col,
                                                     int* __restrict__ gcur,
                                                     unsigned int* __restrict__ packed,
                                                     const float* __restrict__ feat,
                                                     const float* __restrict__ W,
                                                     __half* __restrict__ y) {
    __shared__ float smem[64 * FS + D * D];   // 33.8 KB, shared by both roles
    const int tid = threadIdx.x;

    if (blockIdx.x < NBLKS) {
        // ---- scatter role ----
        int* h      = reinterpret_cast<int*>(smem);       // [256]
        int* base_l = h + NBUK;                           // [256]
        int* rank   = base_l + NBUK;                      // [256]
        const int blk = blockIdx.x;
        h[tid] = 0;
        __syncthreads();
        const uint4* col4 = reinterpret_cast<const uint4*>(col + blk * CHUNK2);
        const uint4* row4 = reinterpret_cast<const uint4*>(row + blk * CHUNK2);
        for (int i = tid; i < CHUNK2 / 4; i += 256) {
            uint4 v = col4[i];
            atomicAdd(&h[v.x >> 8], 1);
            atomicAdd(&h[v.y >> 8], 1);
            atomicAdd(&h[v.z >> 8], 1);
            atomicAdd(&h[v.w >> 8], 1);
        }
        __syncthreads();
        // reserve this block's slice of bucket tid (order nondeterministic,
        // sum-order noise ~1e-6 << 2.8e-2 threshold)
        base_l[tid] = tid * BCAP + atomicAdd(&gcur[tid], h[tid]);
        rank[tid] = 0;
        __syncthreads();
        for (int i = tid; i < CHUNK2 / 4; i += 256) {
            uint4 c4 = col4[i];
            uint4 r4 = row4[i];
            #pragma unroll
            for (int e = 0; e < 4; ++e) {
                unsigned c = (e == 0) ? c4.x : (e == 1) ? c4.y : (e == 2) ? c4.z : c4.w;
                unsigned r = (e == 0) ? r4.x : (e == 1) ? r4.y : (e == 2) ? r4.z : r4.w;
                int bk = c >> 8;
                int rk = atomicAdd(&rank[bk], 1);
                packed[base_l[bk] + rk] = (r & 0xFFFF) | ((c & 0xFF) << 16);
            }
        }
        return;
    }

    // ---- gemm role ----
    float* feat_lds = smem;
    float* W_lds    = smem + 64 * FS;
    const int rbase = (blockIdx.x - NBLKS) * 64;

    {
        const float4* W4  = reinterpret_cast<const float4*>(W);
        float4*       Wl4 = reinterpret_cast<float4*>(W_lds);
        for (int i = tid; i < D * D / 4; i += 256) Wl4[i] = W4[i];
    }
    {
        const int k0 = (tid & 15) * 4;
        #pragma unroll
        for (int it = 0; it < 4; ++it) {
            int r  = it * 16 + (tid >> 4);
            int gr = rbase + r;
            float4 v = make_float4(0.f, 0.f, 0.f, 0.f);
            if (gr < NN) v = *reinterpret_cast<const float4*>(&feat[gr * D + k0]);
            *reinterpret_cast<float4*>(&feat_lds[r * FS + k0]) = v;
        }
    }
    __syncthreads();

    const int tx = tid & 15;
    const int ty = tid >> 4;

    float acc[4][4] = {};

    #pragma unroll 8
    for (int k = 0; k < D; ++k) {
        float4 w = *reinterpret_cast<const float4*>(&W_lds[k * D + tx * 4]);
        float f0 = feat_lds[(ty * 4 + 0) * FS + k];
        float f1 = feat_lds[(ty * 4 + 1) * FS + k];
        float f2 = feat_lds[(ty * 4 + 2) * FS + k];
        float f3 = feat_lds[(ty * 4 + 3) * FS + k];
        acc[0][0] = fmaf(f0, w.x, acc[0][0]); acc[0][1] = fmaf(f0, w.y, acc[0][1]);
        acc[0][2] = fmaf(f0, w.z, acc[0][2]); acc[0][3] = fmaf(f0, w.w, acc[0][3]);
        acc[1][0] = fmaf(f1, w.x, acc[1][0]); acc[1][1] = fmaf(f1, w.y, acc[1][1]);
        acc[1][2] = fmaf(f1, w.z, acc[1][2]); acc[1][3] = fmaf(f1, w.w, acc[1][3]);
        acc[2][0] = fmaf(f2, w.x, acc[2][0]); acc[2][1] = fmaf(f2, w.y, acc[2][1]);
        acc[2][2] = fmaf(f2, w.z, acc[2][2]); acc[2][3] = fmaf(f2, w.w, acc[2][3]);
        acc[3][0] = fmaf(f3, w.x, acc[3][0]); acc[3][1] = fmaf(f3, w.y, acc[3][1]);
        acc[3][2] = fmaf(f3, w.z, acc[3][2]); acc[3][3] = fmaf(f3, w.w, acc[3][3]);
    }

    #pragma unroll
    for (int i = 0; i < 4; ++i) {
        int gr = rbase + ty * 4 + i;
        if (gr < NN) {
            __half2 h0 = __floats2half2_rn(acc[i][0], acc[i][1]);
            __half2 h1 = __floats2half2_rn(acc[i][2], acc[i][3]);
            union { __half2 h[2]; uint2 u; } p;
            p.h[0] = h0; p.h[1] = h1;
            *reinterpret_cast<uint2*>(&y[gr * D + tx * 4]) = p.u;
        }
    }
}

// ---------------------------------------------------------------------------
// K2: per-bucket CSR finalize via LDS, scan-free (fixed segments).
// start = b*BCAP directly; size = gcur[b]. One global read pass into LDS,
// count+scan+scatter in LDS, linear coalesced csr flush. Emits off/cnt/dinv.
__global__ __launch_bounds__(256) void k_csr(const unsigned int* __restrict__ packed,
                                             const int* __restrict__ gcur,
                                             int* __restrict__ off,
                                             int* __restrict__ cnt,
                                             float* __restrict__ dinv,
                                             unsigned short* __restrict__ csr) {
    __shared__ unsigned pk[BCAP];            // 18.4 KB
    __shared__ unsigned short lcsr[BCAP];    // 9.2 KB
    __shared__ int ncnt[NBUK];
    __shared__ int nbase[NBUK];
    __shared__ int rk2[NBUK];
    const int tid = threadIdx.x, b = blockIdx.x;
    const int start = b * BCAP;
    const int size  = min(gcur[b], BCAP);

    ncnt[tid] = 0;
    rk2[tid] = 0;
    __syncthreads();

    for (int i = tid; i < size; i += 256) pk[i] = packed[start + i];
    __syncthreads();
    for (int i = tid; i < size; i += 256)
        atomicAdd(&ncnt[(pk[i] >> 16) & 0xFF], 1);
    __syncthreads();
    int v2  = ncnt[tid];
    int ex2 = block_exscan(v2, tid);
    const int node = b * NBUK + tid;
    off[node]  = start + ex2;
    cnt[node]  = v2;
    dinv[node] = rsqrtf((float)v2 + 1.0f);
    nbase[tid] = ex2;                    // local base within bucket
    __syncthreads();
    for (int i = tid; i < size; i += 256) {
        unsigned u = pk[i];
        int ln = (u >> 16) & 0xFF;
        int rk = atomicAdd(&rk2[ln], 1);
        lcsr[nbase[ln] + rk] = (unsigned short)(u & 0xFFFF);
    }
    __syncthreads();
    for (int i = tid; i < size; i += 256) csr[start + i] = lcsr[i];
}

// ---------------------------------------------------------------------------
// K3: agg (R15 structure): 8-lane group per node, 8 nodes/wave, group-uniform
// guards, 8-deep unconditional gathers, dinv folded into the mask multiplier.
__global__ __launch_bounds__(256, 8) void k_agg8(const unsigned short* __restrict__ csr,
                                                 const int* __restrict__ off,
                                                 const int* __restrict__ cnt,
                                                 const float* __restrict__ dinv,
                                                 const __half* __restrict__ y,
                                                 const float* __restrict__ b,
                                                 float* __restrict__ out) {
    const int lane = threadIdx.x & 63;
    const int g    = lane >> 3;        // group 0..7 = node slot within wave
    const int l8   = lane & 7;         // dim block within the node's row
    const int wave = blockIdx.x * 4 + (threadIdx.x >> 6);
    const int c    = wave * 8 + g;
    const bool valid = (c < NN);

    const uint4* y16 = reinterpret_cast<const uint4*>(y);

    const int s = valid ? off[c] : 0;
    const int n = valid ? cnt[c] : 0;   // group-uniform
    const float dc = valid ? dinv[c] : 0.0f;

    // prefetch up to 32 neighbor ids per group (pre_k = edge l8 + 8k)
    int pre0 = (l8      < n) ? (int)csr[s + l8     ] : 0;
    int pre1 = (l8 + 8  < n) ? (int)csr[s + l8 + 8 ] : 0;
    int pre2 = (l8 + 16 < n) ? (int)csr[s + l8 + 16] : 0;
    int pre3 = (l8 + 24 < n) ? (int)csr[s + l8 + 24] : 0;

    float acc[8] = {0.f, 0.f, 0.f, 0.f, 0.f, 0.f, 0.f, 0.f};

    auto addm = [&](uint4 u, float m) {
        const __half2* h = reinterpret_cast<const __half2*>(&u);
        float2 f0 = __half22float2(h[0]);
        float2 f1 = __half22float2(h[1]);
        float2 f2 = __half22float2(h[2]);
        float2 f3 = __half22float2(h[3]);
        acc[0] = fmaf(m, f0.x, acc[0]); acc[1] = fmaf(m, f0.y, acc[1]);
        acc[2] = fmaf(m, f1.x, acc[2]); acc[3] = fmaf(m, f1.y, acc[3]);
        acc[4] = fmaf(m, f2.x, acc[4]); acc[5] = fmaf(m, f2.y, acc[5]);
        acc[6] = fmaf(m, f3.x, acc[6]); acc[7] = fmaf(m, f3.y, acc[7]);
    };

    // self-loop: weight dinv[c]
    if (valid) addm(y16[c * 8 + l8], dc);

    const int srcb = lane & 56;   // first lane of this group

    #pragma unroll
    for (int w = 0; w < 4; ++w) {
        if (w * 8 < n) {                          // GROUP-uniform guard
            const int pw = (w == 0) ? pre0 : (w == 1) ? pre1
                         : (w == 2) ? pre2 : pre3;
            uint4 u[8];
            float msk[8];
            #pragma unroll
            for (int e = 0; e < 8; ++e) {
                int r = __shfl(pw, srcb + e);     // source within own group
                u[e] = y16[r * 8 + l8];           // 8 in flight per group
                float dv = dinv[r];               // broadcast load
                msk[e] = (w * 8 + e < n) ? dv : 0.0f;
            }
            #pragma unroll
            for (int e = 0; e < 8; ++e) addm(u[e], msk[e]);
        }
    }

    // rare tail (deg > 32): group-divergent, no shfl -> safe
    for (int i = 32; i < n; ++i) {
        int r = (int)csr[s + i];
        addm(y16[r * 8 + l8], dinv[r]);
    }

    if (valid) {
        const float4* b4 = reinterpret_cast<const float4*>(b);
        float4 bb0 = b4[l8 * 2], bb1 = b4[l8 * 2 + 1];
        f32x4 o0, o1;
        o0.x = acc[0] * dc + bb0.x;  o0.y = acc[1] * dc + bb0.y;
        o0.z = acc[2] * dc + bb0.z;  o0.w = acc[3] * dc + bb0.w;
        o1.x = acc[4] * dc + bb1.x;  o1.y = acc[5] * dc + bb1.y;
        o1.z = acc[6] * dc + bb1.z;  o1.w = acc[7] * dc + bb1.w;
        f32x4* out4 = reinterpret_cast<f32x4*>(out);
        __builtin_nontemporal_store(o0, &out4[c * 16 + l8 * 2]);
        __builtin_nontemporal_store(o1, &out4[c * 16 + l8 * 2 + 1]);
    }
}

// ---------------------------------------------------------------------------
extern "C" void kernel_launch(void* const* d_in, const int* in_sizes, int n_in,
                              void* d_out, int out_size, void* d_ws, size_t ws_size,
                              hipStream_t stream) {
    const float* feat = (const float*)d_in[0];   // [NN, D]
    const float* W    = (const float*)d_in[1];   // [D, D]
    const float* b    = (const float*)d_in[2];   // [D]
    const int*   ei   = (const int*)d_in[3];     // [2, NE]
    const int*   row  = ei;                      // sources
    const int*   col  = ei + NE;                 // targets

    float* out = (float*)d_out;                  // [NN, D]

    // workspace layout (~14 MB)
    int*            gcur   = (int*)d_ws;                       // [256] (pad 1024)
    int*            cnt    = gcur + 1024;                      // [65536]
    int*            off    = cnt + 65536;                      // [65536]
    float*          dinv   = (float*)(off + 65536);            // [65536]
    unsigned int*   packed = (unsigned int*)(dinv + 65536);    // [256*BCAP]
    unsigned short* csr    = (unsigned short*)(packed + NBUK * BCAP); // [256*BCAP]
    __half*         y      = (__half*)(csr + NBUK * BCAP);     // [NN*D], 16B-aligned

    hipMemsetAsync(gcur, 0, NBUK * sizeof(int), stream);

    k_gemm_bucket<<<NBLKS + GEMMB, 256, 0, stream>>>(row, col, gcur, packed,
                                                     feat, W, y);
    k_csr <<<NBUK, 256, 0, stream>>>(packed, gcur, off, cnt, dinv, csr);
    k_agg8<<<(NN + 31) / 32, 256, 0, stream>>>(csr, off, cnt, dinv, y, b, out);
}

// Round 17
// 53.945 us; speedup vs baseline: 1.0580x; 1.0580x over previous
//
#include <hip/hip_runtime.h>
#include <hip/hip_fp16.h>

#define NN 50000
#define NE 800000
#define D  64
#define NBUK  256
#define NBLKS 1000           // sort chunks: 1000 x 800 = 800000; 1000 = 8*125
#define CHUNK2 800           // multiple of 4 -> uint4 edge reads
#define HSTR  1024           // H row stride (1000 used, padded)
#define FS 68                // feat LDS stride (pad 64 -> 68)
#define GEMMB 782            // ceil(NN/64) gemm tiles
#define CAP 8192             // k_csr LDS edge capacity (bucket avg 3125*... mean 3125? no: mean NE/NBUK=3125)

typedef float __attribute__((ext_vector_type(4))) f32x4;

// XCD-swizzle: block b (on XCD b%8) owns chunk (b%8)*125 + b/8, so
// consecutive chunk slices within a bucket segment are written by SAME-XCD
// blocks -> no cross-XCD line ping-pong except at 8 boundaries/segment.
__device__ __forceinline__ int chunk_of(int b) { return (b & 7) * 125 + (b >> 3); }

// ---------------------------------------------------------------------------
// block-wide exclusive scan of one int per thread (256 threads = 4 waves).
__device__ inline int block_exscan(int val, int tid) {
    __shared__ int wsum[4];
    int lane = tid & 63, w = tid >> 6;
    int v = val;
    #pragma unroll
    for (int d = 1; d < 64; d <<= 1) {
        int t = __shfl_up(v, d);
        if (lane >= d) v += t;
    }
    if (lane == 63) wsum[w] = v;
    __syncthreads();
    int base = 0;
    #pragma unroll
    for (int i = 0; i < 4; ++i) base += (i < w) ? wsum[i] : 0;
    __syncthreads();
    return base + v - val;   // exclusive
}

// ---------------------------------------------------------------------------
// K1: fused hist + unscaled gemm (independent work, block-role split).
// blocks [0,NBLKS): LDS histogram of col>>8 for chunk chunk_of(b).
// blocks [NBLKS, NBLKS+GEMMB): y_raw[r][d] = fp16(feat[r].W[:,d]).
__global__ __launch_bounds__(256) void k_hist_gemm(const int* __restrict__ col,
                                                   int* __restrict__ H,
                                                   const float* __restrict__ feat,
                                                   const float* __restrict__ W,
                                                   __half* __restrict__ y) {
    __shared__ float smem[64 * FS + D * D];   // 33.8 KB, shared by both roles
    const int tid = threadIdx.x;

    if (blockIdx.x < NBLKS) {
        // ---- histogram role ----
        int* h = reinterpret_cast<int*>(smem);
        const int chunk = chunk_of(blockIdx.x);
        h[tid] = 0;
        __syncthreads();
        const uint4* col4 = reinterpret_cast<const uint4*>(col + chunk * CHUNK2);
        for (int i = tid; i < CHUNK2 / 4; i += 256) {
            uint4 v = col4[i];
            atomicAdd(&h[v.x >> 8], 1);
            atomicAdd(&h[v.y >> 8], 1);
            atomicAdd(&h[v.z >> 8], 1);
            atomicAdd(&h[v.w >> 8], 1);
        }
        __syncthreads();
        H[tid * HSTR + chunk] = h[tid];
        return;
    }

    // ---- gemm role ----
    float* feat_lds = smem;
    float* W_lds    = smem + 64 * FS;
    const int rbase = (blockIdx.x - NBLKS) * 64;

    {
        const float4* W4  = reinterpret_cast<const float4*>(W);
        float4*       Wl4 = reinterpret_cast<float4*>(W_lds);
        for (int i = tid; i < D * D / 4; i += 256) Wl4[i] = W4[i];
    }
    {
        const int k0 = (tid & 15) * 4;
        #pragma unroll
        for (int it = 0; it < 4; ++it) {
            int r  = it * 16 + (tid >> 4);
            int gr = rbase + r;
            float4 v = make_float4(0.f, 0.f, 0.f, 0.f);
            if (gr < NN) v = *reinterpret_cast<const float4*>(&feat[gr * D + k0]);
            *reinterpret_cast<float4*>(&feat_lds[r * FS + k0]) = v;
        }
    }
    __syncthreads();

    const int tx = tid & 15;
    const int ty = tid >> 4;

    float acc[4][4] = {};

    #pragma unroll 8
    for (int k = 0; k < D; ++k) {
        float4 w = *reinterpret_cast<const float4*>(&W_lds[k * D + tx * 4]);
        float f0 = feat_lds[(ty * 4 + 0) * FS + k];
        float f1 = feat_lds[(ty * 4 + 1) * FS + k];
        float f2 = feat_lds[(ty * 4 + 2) * FS + k];
        float f3 = feat_lds[(ty * 4 + 3) * FS + k];
        acc[0][0] = fmaf(f0, w.x, acc[0][0]); acc[0][1] = fmaf(f0, w.y, acc[0][1]);
        acc[0][2] = fmaf(f0, w.z, acc[0][2]); acc[0][3] = fmaf(f0, w.w, acc[0][3]);
        acc[1][0] = fmaf(f1, w.x, acc[1][0]); acc[1][1] = fmaf(f1, w.y, acc[1][1]);
        acc[1][2] = fmaf(f1, w.z, acc[1][2]); acc[1][3] = fmaf(f1, w.w, acc[1][3]);
        acc[2][0] = fmaf(f2, w.x, acc[2][0]); acc[2][1] = fmaf(f2, w.y, acc[2][1]);
        acc[2][2] = fmaf(f2, w.z, acc[2][2]); acc[2][3] = fmaf(f2, w.w, acc[2][3]);
        acc[3][0] = fmaf(f3, w.x, acc[3][0]); acc[3][1] = fmaf(f3, w.y, acc[3][1]);
        acc[3][2] = fmaf(f3, w.z, acc[3][2]); acc[3][3] = fmaf(f3, w.w, acc[3][3]);
    }

    #pragma unroll
    for (int i = 0; i < 4; ++i) {
        int gr = rbase + ty * 4 + i;
        if (gr < NN) {
            __half2 h0 = __floats2half2_rn(acc[i][0], acc[i][1]);
            __half2 h1 = __floats2half2_rn(acc[i][2], acc[i][3]);
            union { __half2 h[2]; uint2 u; } p;
            p.h[0] = h0; p.h[1] = h1;
            *reinterpret_cast<uint2*>(&y[gr * D + tx * 4]) = p.u;
        }
    }
}

// ---------------------------------------------------------------------------
// K2: per-bucket exclusive scan over the 1000 chunk entries (4 per thread).
__global__ __launch_bounds__(256) void k_scanA(int* __restrict__ H,
                                               int* __restrict__ bsum) {
    const int tid = threadIdx.x, bkt = blockIdx.x;
    int* Hb = H + bkt * HSTR;
    int v0 = 0, v1 = 0, v2 = 0, v3 = 0;
    if (tid < 250) {
        v0 = Hb[4 * tid];     v1 = Hb[4 * tid + 1];
        v2 = Hb[4 * tid + 2]; v3 = Hb[4 * tid + 3];
    }
    int sum = v0 + v1 + v2 + v3;
    int ex = block_exscan(sum, tid);
    if (tid < 250) {
        Hb[4 * tid]     = ex;
        Hb[4 * tid + 1] = ex + v0;
        Hb[4 * tid + 2] = ex + v0 + v1;
        Hb[4 * tid + 3] = ex + v0 + v1 + v2;
    }
    if (tid == 255) bsum[bkt] = ex;   // tid 255 has sum=0 -> ex == grand total
}

// ---------------------------------------------------------------------------
// K3: scatter edges into bucket segments as packed (row | (col&255)<<16).
// Block b processes chunk_of(b): same-XCD blocks own adjacent segment slices.
__global__ __launch_bounds__(256) void k_bucket(const int* __restrict__ row,
                                                const int* __restrict__ col,
                                                const int* __restrict__ H,
                                                const int* __restrict__ bsum,
                                                unsigned int* __restrict__ packed) {
    __shared__ int base_l[NBUK];
    __shared__ int rank[NBUK];
    const int tid = threadIdx.x;
    const int chunk = chunk_of(blockIdx.x);
    int ex = block_exscan(bsum[tid], tid);      // global bucket base
    base_l[tid] = ex + H[tid * HSTR + chunk];   // + this chunk's offset
    rank[tid] = 0;
    __syncthreads();
    const uint4* col4 = reinterpret_cast<const uint4*>(col + chunk * CHUNK2);
    const uint4* row4 = reinterpret_cast<const uint4*>(row + chunk * CHUNK2);
    for (int i = tid; i < CHUNK2 / 4; i += 256) {
        uint4 c4 = col4[i];
        uint4 r4 = row4[i];
        #pragma unroll
        for (int e = 0; e < 4; ++e) {
            unsigned c = (e == 0) ? c4.x : (e == 1) ? c4.y : (e == 2) ? c4.z : c4.w;
            unsigned r = (e == 0) ? r4.x : (e == 1) ? r4.y : (e == 2) ? r4.z : r4.w;
            int bk = c >> 8;
            int rk = atomicAdd(&rank[bk], 1);
            packed[base_l[bk] + rk] = (r & 0xFFFF) | ((c & 0xFF) << 16);
        }
    }
}

// ---------------------------------------------------------------------------
// K4: per-bucket CSR finalize, single global pass via LDS staging (R15).
__global__ __launch_bounds__(256) void k_csr(const unsigned int* __restrict__ packed,
                                             const int* __restrict__ bsum,
                                             int* __restrict__ off,
                                             int* __restrict__ cnt,
                                             float* __restrict__ dinv,
                                             unsigned short* __restrict__ csr) {
    __shared__ unsigned pk[CAP];            // 32 KB
    __shared__ unsigned short lcsr[CAP];    // 16 KB
    __shared__ int ncnt[NBUK];
    __shared__ int nbase[NBUK];
    __shared__ int rk2[NBUK];
    __shared__ int sstart;
    const int tid = threadIdx.x, b = blockIdx.x;

    int ex = block_exscan(bsum[tid], tid);
    if (tid == b) sstart = ex;
    ncnt[tid] = 0;
    rk2[tid] = 0;
    __syncthreads();

    const int start = sstart;
    const int size  = bsum[b];

    if (size <= CAP) {
        for (int i = tid; i < size; i += 256) pk[i] = packed[start + i];
        __syncthreads();
        for (int i = tid; i < size; i += 256)
            atomicAdd(&ncnt[(pk[i] >> 16) & 0xFF], 1);
        __syncthreads();
        int v2  = ncnt[tid];
        int ex2 = block_exscan(v2, tid);
        const int node = b * NBUK + tid;
        off[node]  = start + ex2;
        cnt[node]  = v2;
        dinv[node] = rsqrtf((float)v2 + 1.0f);
        nbase[tid] = ex2;                    // LOCAL base within bucket
        __syncthreads();
        for (int i = tid; i < size; i += 256) {
            unsigned u = pk[i];
            int ln = (u >> 16) & 0xFF;
            int rk = atomicAdd(&rk2[ln], 1);
            lcsr[nbase[ln] + rk] = (unsigned short)(u & 0xFFFF);
        }
        __syncthreads();
        for (int i = tid; i < size; i += 256) csr[start + i] = lcsr[i];
    } else {
        for (int i = tid; i < size; i += 256)
            atomicAdd(&ncnt[(packed[start + i] >> 16) & 0xFF], 1);
        __syncthreads();
        int v2  = ncnt[tid];
        int ex2 = block_exscan(v2, tid);
        const int node = b * NBUK + tid;
        off[node]  = start + ex2;
        cnt[node]  = v2;
        dinv[node] = rsqrtf((float)v2 + 1.0f);
        nbase[tid] = start + ex2;
        __syncthreads();
        for (int i = tid; i < size; i += 256) {
            unsigned u = packed[start + i];
            int ln = (u >> 16) & 0xFF;
            int rk = atomicAdd(&rk2[ln], 1);
            csr[nbase[ln] + rk] = (unsigned short)(u & 0xFFFF);
        }
    }
}

// ---------------------------------------------------------------------------
// K5: agg (R15 structure): 8-lane group per node, 8 nodes/wave, group-uniform
// guards, 8-deep unconditional gathers, dinv folded into the mask multiplier.
__global__ __launch_bounds__(256, 8) void k_agg8(const unsigned short* __restrict__ csr,
                                                 const int* __restrict__ off,
                                                 const int* __restrict__ cnt,
                                                 const float* __restrict__ dinv,
                                                 const __half* __restrict__ y,
                                                 const float* __restrict__ b,
                                                 float* __restrict__ out) {
    const int lane = threadIdx.x & 63;
    const int g    = lane >> 3;        // group 0..7 = node slot within wave
    const int l8   = lane & 7;         // dim block within the node's row
    const int wave = blockIdx.x * 4 + (threadIdx.x >> 6);
    const int c    = wave * 8 + g;
    const bool valid = (c < NN);

    const uint4* y16 = reinterpret_cast<const uint4*>(y);

    const int s = valid ? off[c] : 0;
    const int n = valid ? cnt[c] : 0;   // group-uniform
    const float dc = valid ? dinv[c] : 0.0f;

    int pre0 = (l8      < n) ? (int)csr[s + l8     ] : 0;
    int pre1 = (l8 + 8  < n) ? (int)csr[s + l8 + 8 ] : 0;
    int pre2 = (l8 + 16 < n) ? (int)csr[s + l8 + 16] : 0;
    int pre3 = (l8 + 24 < n) ? (int)csr[s + l8 + 24] : 0;

    float acc[8] = {0.f, 0.f, 0.f, 0.f, 0.f, 0.f, 0.f, 0.f};

    auto addm = [&](uint4 u, float m) {
        const __half2* h = reinterpret_cast<const __half2*>(&u);
        float2 f0 = __half22float2(h[0]);
        float2 f1 = __half22float2(h[1]);
        float2 f2 = __half22float2(h[2]);
        float2 f3 = __half22float2(h[3]);
        acc[0] = fmaf(m, f0.x, acc[0]); acc[1] = fmaf(m, f0.y, acc[1]);
        acc[2] = fmaf(m, f1.x, acc[2]); acc[3] = fmaf(m, f1.y, acc[3]);
        acc[4] = fmaf(m, f2.x, acc[4]); acc[5] = fmaf(m, f2.y, acc[5]);
        acc[6] = fmaf(m, f3.x, acc[6]); acc[7] = fmaf(m, f3.y, acc[7]);
    };

    if (valid) addm(y16[c * 8 + l8], dc);   // self-loop

    const int srcb = lane & 56;   // first lane of this group

    #pragma unroll
    for (int w = 0; w < 4; ++w) {
        if (w * 8 < n) {                          // GROUP-uniform guard
            const int pw = (w == 0) ? pre0 : (w == 1) ? pre1
                         : (w == 2) ? pre2 : pre3;
            uint4 u[8];
            float msk[8];
            #pragma unroll
            for (int e = 0; e < 8; ++e) {
                int r = __shfl(pw, srcb + e);     // source within own group
                u[e] = y16[r * 8 + l8];           // 8 in flight per group
                float dv = dinv[r];               // broadcast load
                msk[e] = (w * 8 + e < n) ? dv : 0.0f;
            }
            #pragma unroll
            for (int e = 0; e < 8; ++e) addm(u[e], msk[e]);
        }
    }

    for (int i = 32; i < n; ++i) {               // rare tail (deg > 32)
        int r = (int)csr[s + i];
        addm(y16[r * 8 + l8], dinv[r]);
    }

    if (valid) {
        const float4* b4 = reinterpret_cast<const float4*>(b);
        float4 bb0 = b4[l8 * 2], bb1 = b4[l8 * 2 + 1];
        f32x4 o0, o1;
        o0.x = acc[0] * dc + bb0.x;  o0.y = acc[1] * dc + bb0.y;
        o0.z = acc[2] * dc + bb0.z;  o0.w = acc[3] * dc + bb0.w;
        o1.x = acc[4] * dc + bb1.x;  o1.y = acc[5] * dc + bb1.y;
        o1.z = acc[6] * dc + bb1.z;  o1.w = acc[7] * dc + bb1.w;
        f32x4* out4 = reinterpret_cast<f32x4*>(out);
        __builtin_nontemporal_store(o0, &out4[c * 16 + l8 * 2]);
        __builtin_nontemporal_store(o1, &out4[c * 16 + l8 * 2 + 1]);
    }
}

// ---------------------------------------------------------------------------
extern "C" void kernel_launch(void* const* d_in, const int* in_sizes, int n_in,
                              void* d_out, int out_size, void* d_ws, size_t ws_size,
                              hipStream_t stream) {
    const float* feat = (const float*)d_in[0];   // [NN, D]
    const float* W    = (const float*)d_in[1];   // [D, D]
    const float* b    = (const float*)d_in[2];   // [D]
    const int*   ei   = (const int*)d_in[3];     // [2, NE]
    const int*   row  = ei;                      // sources
    const int*   col  = ei + NE;                 // targets

    float* out = (float*)d_out;                  // [NN, D]

    // workspace layout (~14 MB)
    int*            H      = (int*)d_ws;                      // [256*HSTR]
    int*            bsum   = H + NBUK * HSTR;                 // [256] (pad 1024)
    int*            cnt    = bsum + 1024;                     // [65536]
    int*            off    = cnt + 65536;                     // [65536]
    float*          dinv   = (float*)(off + 65536);           // [65536]
    unsigned int*   packed = (unsigned int*)(dinv + 65536);   // [NE]
    unsigned short* csr    = (unsigned short*)(packed + NE);  // [NE]
    __half*         y      = (__half*)(csr + NE);             // [NN*D], 16B-aligned

    k_hist_gemm<<<NBLKS + GEMMB, 256, 0, stream>>>(col, H, feat, W, y);
    k_scanA    <<<NBUK,  256, 0, stream>>>(H, bsum);
    k_bucket   <<<NBLKS, 256, 0, stream>>>(row, col, H, bsum, packed);
    k_csr      <<<NBUK,  256, 0, stream>>>(packed, bsum, off, cnt, dinv, csr);
    k_agg8     <<<(NN + 31) / 32, 256, 0, stream>>>(csr, off, cnt, dinv, y, b, out);
}